// Round 12
// baseline (191.451 us; speedup 1.0000x reference)
//
#include <hip/hip_runtime.h>
#include <hip/hip_bf16.h>
#include <cstdint>
#include <math.h>

#define BATCH 4
#define SDIM  2048
#define DDIM  1024
#define QKVN  3072   // fused Q|K|V output width

typedef __attribute__((ext_vector_type(8))) short bf16x8;
typedef __attribute__((ext_vector_type(4))) float f32x4;

__device__ __forceinline__ float bf2f(unsigned short u) {
  union { unsigned int i; float f; } v; v.i = ((unsigned int)u) << 16; return v.f;
}
__device__ __forceinline__ unsigned short f2bf(float f) {
  unsigned int i = __float_as_uint(f);
  return (unsigned short)((i + 0x7FFFu + ((i >> 16) & 1u)) >> 16);  // RNE
}

#define GLOAD16(gp, lp) \
  __builtin_amdgcn_global_load_lds((const __attribute__((address_space(1))) void*)(gp), \
                                   (__attribute__((address_space(3))) void*)(lp), 16, 0, 0)

// ---------------- all fp32 -> bf16 converts in ONE dispatch ----------------
// dest = ws: [ xb 8M | Wq 1M | Wk 1M | Wv 1M | Wo 1M ] shorts (contiguous)
__global__ void cvt_all(const float* __restrict__ x,  const float* __restrict__ wq,
                        const float* __restrict__ wk, const float* __restrict__ wv,
                        const float* __restrict__ wo, unsigned short* __restrict__ out) {
  const int NX = 8 * 1024 * 1024, NW = 1024 * 1024;
  const int total = NX + 4 * NW;
  int i0 = (blockIdx.x * 256 + threadIdx.x) * 4;
  const int stride = gridDim.x * 256 * 4;
  for (int i = i0; i < total; i += stride) {
    const float* src;
    int off;
    if (i < NX)               { src = x;  off = i; }
    else if (i < NX + NW)     { src = wq; off = i - NX; }
    else if (i < NX + 2 * NW) { src = wk; off = i - NX - NW; }
    else if (i < NX + 3 * NW) { src = wv; off = i - NX - 2 * NW; }
    else                      { src = wo; off = i - NX - 3 * NW; }
    float4 v = *reinterpret_cast<const float4*>(src + off);
    ushort4 o;
    o.x = f2bf(v.x); o.y = f2bf(v.y); o.z = f2bf(v.z); o.w = f2bf(v.w);
    *reinterpret_cast<ushort4*>(out + i) = o;
  }
}

// ============ 128x128 tri-buffered MFMA GEMM (proven R3 engine) ==============
// NT: C[m,n] = sum_k A[m,k]*B[n,k]; bf16, K contiguous. Tri-buffer BK=32,
// counted vmcnt(4) (tail drains 0), zero-conflict row-pair XOR swizzle.
// MODE 0: QKV: A=xb[8192,1024] B=Wqkv[3072,1024] C=bf16[8192,3072]+bias(sel)
//   1536 blocks = exactly 2 rounds of 768 slots (no tail waste);
//   xcd = f&7 owns a ti band of 8; tj outer (B-tile reuse within XCD).
// MODE 1: PV+out: per-batch, A=P[b][2048,2048] B=VWo_t[b][1024,2048],
//   K=(ti+1)*128; xcd owns one batch-half of tj;
//   ti = (tr<8)? tr : 23-tr  (bijective; CU-pair work = const 17 K-tiles);
//   rowinv from aux partials in prologue; C = fp32 out = v*rowinv + bo.
template<int MODE>
__global__ __launch_bounds__(256, 3)
void gemm_kernel(const unsigned short* __restrict__ A,
                 const unsigned short* __restrict__ B,
                 const float* __restrict__ bias0,
                 const float* __restrict__ bias1,
                 const float* __restrict__ bias2,
                 const float* __restrict__ aux,
                 void* __restrict__ C)
{
  __shared__ unsigned short As[3][128 * 32];
  __shared__ unsigned short Bs[3][128 * 32];
  __shared__ float rowinv[128];   // MODE 1 only

  const int tid  = threadIdx.x;
  const int wave = tid >> 6;
  const int lane = tid & 63;
  const int wr   = wave >> 1;
  const int wc   = wave & 1;

  const unsigned short *Ab, *Bb;
  int lda, ldb, ktiles;
  int ti, tj, bz = 0;

  if constexpr (MODE == 0) {
    const int f = blockIdx.x;
    const int xcd = f & 7, s = f >> 3;        // s: 0..191
    ti = xcd * 8 + (s & 7);                   // 0..63
    tj = s >> 3;                              // 0..23
    Ab = A + (size_t)ti * 128 * DDIM;  lda = DDIM;
    Bb = B + (size_t)tj * 128 * DDIM;  ldb = DDIM;
    ktiles = DDIM / 32;
  } else { // MODE 1: PV + output write, 512 blocks 1D
    const int f = blockIdx.x;
    const int xcd = f & 7, idx = f >> 3;      // idx: 0..63
    bz = xcd >> 1;
    tj = (xcd & 1) * 4 + (idx & 3);           // 0..7
    const int tr = idx >> 2;                  // 0..15
    ti = (tr < 8) ? tr : (23 - tr);           // bijective, CU-pair balanced
    Ab = A + (size_t)bz * SDIM * SDIM + (size_t)ti * 128 * SDIM; lda = SDIM;
    Bb = B + (size_t)bz * DDIM * SDIM + (size_t)tj * 128 * SDIM; ldb = SDIM;
    ktiles = (ti + 1) * 4;

    if (tid < 128) {
      const int gi = ti * 128 + tid;
      const float* p = aux + ((size_t)bz * SDIM + gi) * 32;
      float s = 0.f;
      const int n = 2 * (ti + 1);
      for (int j = 0; j < n; ++j) s += p[j];
      rowinv[tid] = 1.0f / s;      // s >= exp(0) = 1
    }
    __syncthreads();
  }

  f32x4 acc[4][4];
#pragma unroll
  for (int i = 0; i < 4; ++i)
#pragma unroll
    for (int j = 0; j < 4; ++j) acc[i][j] = (f32x4){0.f, 0.f, 0.f, 0.f};

  const int g0   = (lane & 7) ^ (lane >> 3);
  const int rloc = 2 * (lane >> 3) + (g0 >> 2);
  const int colg = (g0 & 3) * 8;

  const int s_  = lane >> 4;
  const int fr  = lane & 15;
  const int p_  = (((fr & 1) << 2) | s_) ^ ((fr >> 1) & 7);
  const int fA  = wr * 2048 + (fr >> 1) * 64 + p_ * 8;
  const int fB  = wc * 2048 + (fr >> 1) * 64 + p_ * 8;

#define STAGE(buf, kt) do {                                                     \
    const size_t kb_ = (size_t)(kt) * 32 + colg;                                \
    GLOAD16(Ab + (size_t)(wave * 16 + rloc) * lda + kb_,      &As[buf][wave * 512]);       \
    GLOAD16(Ab + (size_t)(64 + wave * 16 + rloc) * lda + kb_, &As[buf][(wave + 4) * 512]); \
    GLOAD16(Bb + (size_t)(wave * 16 + rloc) * ldb + kb_,      &Bs[buf][wave * 512]);       \
    GLOAD16(Bb + (size_t)(64 + wave * 16 + rloc) * ldb + kb_, &Bs[buf][(wave + 4) * 512]); \
  } while (0)

  STAGE(0, 0);
  STAGE(1, 1);
  asm volatile("s_waitcnt vmcnt(4)" ::: "memory");
  __builtin_amdgcn_s_barrier();
  __builtin_amdgcn_sched_barrier(0);

  for (int kt = 0; kt < ktiles; ++kt) {
    const int cur = kt % 3;
    const bool st = (kt + 2 < ktiles);
    if (st) STAGE((kt + 2) % 3, kt + 2);

    bf16x8 af[4], bfv[4];
#pragma unroll
    for (int mi = 0; mi < 4; ++mi)
      af[mi] = *reinterpret_cast<const bf16x8*>(&As[cur][fA + mi * 512]);
#pragma unroll
    for (int ni = 0; ni < 4; ++ni)
      bfv[ni] = *reinterpret_cast<const bf16x8*>(&Bs[cur][fB + ni * 512]);

    __builtin_amdgcn_s_setprio(1);
#pragma unroll
    for (int mi = 0; mi < 4; ++mi)
#pragma unroll
      for (int ni = 0; ni < 4; ++ni)
        acc[mi][ni] = __builtin_amdgcn_mfma_f32_16x16x32_bf16(af[mi], bfv[ni], acc[mi][ni], 0, 0, 0);
    __builtin_amdgcn_s_setprio(0);

    if (st) { asm volatile("s_waitcnt vmcnt(4)" ::: "memory"); }
    else    { asm volatile("s_waitcnt vmcnt(0)" ::: "memory"); }
    __builtin_amdgcn_s_barrier();
    __builtin_amdgcn_sched_barrier(0);
  }
#undef STAGE

  const int row0 = wr * 64, col0 = wc * 64;
  const float* bp = bias0;
  if constexpr (MODE == 0) bp = (tj < 8) ? bias0 : ((tj < 16) ? bias1 : bias2);
#pragma unroll
  for (int mi = 0; mi < 4; ++mi) {
#pragma unroll
    for (int ni = 0; ni < 4; ++ni) {
#pragma unroll
      for (int r = 0; r < 4; ++r) {
        const int lr = row0 + mi * 16 + (lane >> 4) * 4 + r;
        const int lc = col0 + ni * 16 + (lane & 15);
        const float v = acc[mi][ni][r];
        if constexpr (MODE == 0) {
          const int gr = ti * 128 + lr, gc = tj * 128 + lc;
          ((unsigned short*)C)[(size_t)gr * QKVN + gc] = f2bf(v + bp[gc & 1023]);
        } else { // MODE 1: final output, fp32, normalized + bias
          const int gi = ti * 128 + lr, gd = tj * 128 + lc;
          ((float*)C)[((size_t)bz * SDIM + gi) * DDIM + gd] = v * rowinv[lr] + bias0[gd];
        }
      }
    }
  }
}

// ====== scores + VWo^T: persistent work-stealing kernel ======================
// 1056 uniform tiles (t<544: scores; t>=544: VWo^T), grid = 768 (3/CU slots).
// Blocks loop t = atomicAdd(counter) -> work-conserving packing (fixes the
// 768+288 two-round tail that capped fill at 69%). Each tile computed exactly
// once, outputs at unique addresses -> deterministic regardless of mapping.
__global__ __launch_bounds__(256, 3)
void attn_prep(const unsigned short* __restrict__ QKVb,
               const unsigned short* __restrict__ wo,
               float* __restrict__ partial,
               unsigned short* __restrict__ Sc,
               unsigned short* __restrict__ VWo_t,
               unsigned int* __restrict__ counter)
{
  __shared__ unsigned short As[3][128 * 32];
  __shared__ unsigned short Bs[3][128 * 32];
  __shared__ unsigned int t_sh;

  const int tid  = threadIdx.x;
  const int wave = tid >> 6;
  const int lane = tid & 63;
  const int wr   = wave >> 1;
  const int wc   = wave & 1;

  // per-lane engine constants (hoisted out of the work loop)
  const int g0   = (lane & 7) ^ (lane >> 3);
  const int rloc = 2 * (lane >> 3) + (g0 >> 2);
  const int colg = (g0 & 3) * 8;
  const int s_  = lane >> 4;
  const int fr  = lane & 15;
  const int p_  = (((fr & 1) << 2) | s_) ^ ((fr >> 1) & 7);
  const int fA  = wr * 2048 + (fr >> 1) * 64 + p_ * 8;
  const int fB  = wc * 2048 + (fr >> 1) * 64 + p_ * 8;

  for (;;) {
    if (tid == 0) t_sh = atomicAdd(counter, 1u);
    __syncthreads();
    const int t = (int)t_sh;
    if (t >= 1056) break;     // uniform across block

    const bool is_score = (t < 544);
    const unsigned short *Ab, *Bb;
    int lda, ldb, ti, tj, bz;

    if (is_score) {
      bz = t / 136;
      int tt = t - bz * 136;
      ti = 0;
      while ((ti + 1) * (ti + 2) / 2 <= tt) ++ti;   // triangular decode
      tj = tt - ti * (ti + 1) / 2;                  // tj <= ti
      Ab = QKVb + (size_t)bz * SDIM * QKVN + (size_t)ti * 128 * QKVN;        lda = QKVN; // Q
      Bb = QKVb + (size_t)bz * SDIM * QKVN + (size_t)tj * 128 * QKVN + 1024; ldb = QKVN; // K
    } else {
      const int v = t - 544;                        // 0..511
      bz = v >> 7;
      const int idx = v & 127;
      ti = idx >> 4;                                // Wo row tile (d), 0..7
      tj = idx & 15;                                // V row tile (s), 0..15
      Ab = wo + (size_t)ti * 128 * DDIM;                                     lda = DDIM;
      Bb = QKVb + (size_t)bz * SDIM * QKVN + (size_t)tj * 128 * QKVN + 2048; ldb = QKVN; // V
    }
    const int ktiles = DDIM / 32;

    f32x4 acc[4][4];
#pragma unroll
    for (int i = 0; i < 4; ++i)
#pragma unroll
      for (int j = 0; j < 4; ++j) acc[i][j] = (f32x4){0.f, 0.f, 0.f, 0.f};

#define STAGE2(buf, kt) do {                                                    \
    const size_t kb_ = (size_t)(kt) * 32 + colg;                                \
    GLOAD16(Ab + (size_t)(wave * 16 + rloc) * lda + kb_,      &As[buf][wave * 512]);       \
    GLOAD16(Ab + (size_t)(64 + wave * 16 + rloc) * lda + kb_, &As[buf][(wave + 4) * 512]); \
    GLOAD16(Bb + (size_t)(wave * 16 + rloc) * ldb + kb_,      &Bs[buf][wave * 512]);       \
    GLOAD16(Bb + (size_t)(64 + wave * 16 + rloc) * ldb + kb_, &Bs[buf][(wave + 4) * 512]); \
  } while (0)

    STAGE2(0, 0);
    STAGE2(1, 1);
    asm volatile("s_waitcnt vmcnt(4)" ::: "memory");
    __builtin_amdgcn_s_barrier();
    __builtin_amdgcn_sched_barrier(0);

    for (int kt = 0; kt < ktiles; ++kt) {
      const int cur = kt % 3;
      const bool st = (kt + 2 < ktiles);
      if (st) STAGE2((kt + 2) % 3, kt + 2);

      bf16x8 af[4], bfv[4];
#pragma unroll
      for (int mi = 0; mi < 4; ++mi)
        af[mi] = *reinterpret_cast<const bf16x8*>(&As[cur][fA + mi * 512]);
#pragma unroll
      for (int ni = 0; ni < 4; ++ni)
        bfv[ni] = *reinterpret_cast<const bf16x8*>(&Bs[cur][fB + ni * 512]);

      __builtin_amdgcn_s_setprio(1);
#pragma unroll
      for (int mi = 0; mi < 4; ++mi)
#pragma unroll
        for (int ni = 0; ni < 4; ++ni)
          acc[mi][ni] = __builtin_amdgcn_mfma_f32_16x16x32_bf16(af[mi], bfv[ni], acc[mi][ni], 0, 0, 0);
      __builtin_amdgcn_s_setprio(0);

      if (st) { asm volatile("s_waitcnt vmcnt(4)" ::: "memory"); }
      else    { asm volatile("s_waitcnt vmcnt(0)" ::: "memory"); }
      __builtin_amdgcn_s_barrier();
      __builtin_amdgcn_sched_barrier(0);
    }
#undef STAGE2

    const int row0 = wr * 64, col0 = wc * 64;
    if (is_score) {
      // P = exp(|s|/32) (0 above diag), bf16-rounded; per-row partial sums
#pragma unroll
      for (int mi = 0; mi < 4; ++mi) {
#pragma unroll
        for (int r = 0; r < 4; ++r) {
          const int gi = ti * 128 + row0 + mi * 16 + (lane >> 4) * 4 + r;
          float ps = 0.f;
#pragma unroll
          for (int ni = 0; ni < 4; ++ni) {
            const int gj = tj * 128 + col0 + ni * 16 + (lane & 15);
            float p = (gj > gi) ? 0.f : __expf(fabsf(acc[mi][ni][r]) * 0.03125f);
            unsigned short us = f2bf(p);
            Sc[(size_t)bz * SDIM * SDIM + (size_t)gi * SDIM + gj] = us;
            ps += bf2f(us);
          }
          ps += __shfl_xor(ps, 1);
          ps += __shfl_xor(ps, 2);
          ps += __shfl_xor(ps, 4);
          ps += __shfl_xor(ps, 8);
          if ((lane & 15) == 0)
            partial[((size_t)bz * SDIM + gi) * 32 + tj * 2 + wc] = ps;
        }
      }
    } else {
      // VWo^T tile: [d, s] row-major, ld = SDIM
#pragma unroll
      for (int mi = 0; mi < 4; ++mi) {
#pragma unroll
        for (int ni = 0; ni < 4; ++ni) {
#pragma unroll
          for (int r = 0; r < 4; ++r) {
            const int gd = ti * 128 + row0 + mi * 16 + (lane >> 4) * 4 + r;
            const int gs = tj * 128 + col0 + ni * 16 + (lane & 15);
            VWo_t[(size_t)bz * DDIM * SDIM + (size_t)gd * SDIM + gs] = f2bf(acc[mi][ni][r]);
          }
        }
      }
    }
    // loop: next atomic grab (t_sh rewritten only after the __syncthreads
    // at the top; all threads have already consumed t into a register)
  }
}

// ---------------- host launch ----------------
extern "C" void kernel_launch(void* const* d_in, const int* in_sizes, int n_in,
                              void* d_out, int out_size, void* d_ws, size_t ws_size,
                              hipStream_t stream) {
  const float* x  = (const float*)d_in[0];
  const float* Wq = (const float*)d_in[1];
  const float* bq = (const float*)d_in[2];
  const float* Wk = (const float*)d_in[3];
  const float* bk = (const float*)d_in[4];
  const float* Wv = (const float*)d_in[5];
  const float* bv = (const float*)d_in[6];
  const float* Wo = (const float*)d_in[7];
  const float* bo = (const float*)d_in[8];
  float* out = (float*)d_out;

  const size_t NTOK = (size_t)BATCH * SDIM;       // 8192
  unsigned short* ws = (unsigned short*)d_ws;
  unsigned short* xb   = ws;                          // [8192,1024]
  unsigned short* wqkv = xb + NTOK * DDIM;            // [3072,1024]
  unsigned short* wo   = wqkv + (size_t)QKVN * DDIM;  // [1024,1024]
  unsigned short* QKVb = wo + (size_t)DDIM * DDIM;    // [8192,3072]
  unsigned short* VWot = QKVb + NTOK * QKVN;          // [B,1024,2048] = (V@Wo^T)^T
  unsigned short* Sc   = VWot + NTOK * DDIM;          // [B,2048,2048] = P (exp)
  float* partial = (float*)(Sc + (size_t)BATCH * SDIM * SDIM);  // [8192][32]
  unsigned int* counter = (unsigned int*)(partial + NTOK * 32);

  // all converts in one dispatch (dest regions contiguous from ws)
  cvt_all<<<2048, 256, 0, stream>>>(x, Wq, Wk, Wv, Wo, xb);

  // fused QKV projection -> QKVb [8192, 3072]  (2 exact rounds of 768)
  gemm_kernel<0><<<1536, 256, 0, stream>>>(xb, wqkv, bq, bk, bv, nullptr, QKVb);

  // scores (P=exp, partials) || VWo^T — persistent work-stealing over 1056 tiles
  hipMemsetAsync(counter, 0, sizeof(unsigned int), stream);
  attn_prep<<<768, 256, 0, stream>>>(QKVb, wo, partial, Sc, VWot, counter);

  // out = rowInv * (P @ VWo^T) + bo  (1D grid, XCD batch-half + balanced ti)
  gemm_kernel<1><<<512, 256, 0, stream>>>(Sc, VWot, bo, nullptr, nullptr,
                                          partial, out);
}